// Round 1
// baseline (961.890 us; speedup 1.0000x reference)
//
#include <hip/hip_runtime.h>
#include <math.h>

#define SEQ 512
#define NORD 256
#define MODES 32
#define KBIG (NORD*MODES*2)   // 16384
#define PI_F 3.14159265358979323846f

// ---------------- generic job-based f32 GEMM (64x64 tile, 256 thr, 4x4 micro) ----

struct GemmJob {
  const float* A; const float* B; float* C; const float* scale_ptr;
  int M, N, lda, k0, k1, atomic;
};
struct GemmJobs { GemmJob j[16]; };

__global__ __launch_bounds__(256) void gemm_k(GemmJobs P) {
  GemmJob jb = P.j[blockIdx.z];
  int row0 = blockIdx.x * 64, col0 = blockIdx.y * 64;
  if (row0 >= jb.M || col0 >= jb.N) return;
  __shared__ __align__(16) float As[16][68];
  __shared__ __align__(16) float Bs[16][68];
  int tid = threadIdx.x;
  int tx = tid & 15, ty = tid >> 4;
  float acc[4][4] = {{0.f}};
  const float* A = jb.A; const float* B = jb.B;
  int M = jb.M, N = jb.N, lda = jb.lda;
  for (int kb = jb.k0; kb < jb.k1; kb += 16) {
    #pragma unroll
    for (int rr = 0; rr < 4; rr++) {
      int r = ty + rr * 16;
      int gr = row0 + r;
      float v = 0.f;
      if (gr < M) v = A[(size_t)gr * lda + kb + tx];
      As[tx][r] = v;
    }
    #pragma unroll
    for (int rr = 0; rr < 4; rr++) {
      int kk = (tid >> 6) + rr * 4;
      int cc = tid & 63;
      Bs[kk][cc] = B[(size_t)(kb + kk) * N + col0 + cc];
    }
    __syncthreads();
    #pragma unroll
    for (int kk = 0; kk < 16; kk++) {
      float4 a = *(const float4*)&As[kk][ty * 4];
      float4 b = *(const float4*)&Bs[kk][tx * 4];
      acc[0][0] += a.x*b.x; acc[0][1] += a.x*b.y; acc[0][2] += a.x*b.z; acc[0][3] += a.x*b.w;
      acc[1][0] += a.y*b.x; acc[1][1] += a.y*b.y; acc[1][2] += a.y*b.z; acc[1][3] += a.y*b.w;
      acc[2][0] += a.z*b.x; acc[2][1] += a.z*b.y; acc[2][2] += a.z*b.z; acc[2][3] += a.z*b.w;
      acc[3][0] += a.w*b.x; acc[3][1] += a.w*b.y; acc[3][2] += a.w*b.z; acc[3][3] += a.w*b.w;
    }
    __syncthreads();
  }
  float sc = jb.scale_ptr ? *jb.scale_ptr : 1.f;
  int r0 = row0 + ty * 4, c0 = col0 + tx * 4;
  #pragma unroll
  for (int i = 0; i < 4; i++) {
    int gr = r0 + i;
    if (gr < M) {
      #pragma unroll
      for (int jjj = 0; jjj < 4; jjj++) {
        float v = acc[i][jjj] * sc;
        if (jb.atomic) atomicAdd(&jb.C[(size_t)gr * N + c0 + jjj], v);
        else jb.C[(size_t)gr * N + c0 + jjj] = v;
      }
    }
  }
}

// ---------------- small helpers ----------------

__global__ __launch_bounds__(256) void zerobuf_k(float* p, int n) {
  int i = blockIdx.x * 256 + threadIdx.x;
  if (i < n) p[i] = 0.f;
}

// RevIN: per (b,c) mean/std over L, normalize, write F [512 rows x 512 t]
__global__ __launch_bounds__(256) void revin_k(const float* __restrict__ x,
                                               const float* __restrict__ aw,
                                               const float* __restrict__ ab,
                                               float* __restrict__ F,
                                               float* __restrict__ stats) {
  int row = blockIdx.x;            // b*32 + c
  int b = row >> 5, c = row & 31;
  int tid = threadIdx.x;
  const float* xp = x + (size_t)b * SEQ * 32 + c;
  float v0 = xp[(size_t)tid * 32];
  float v1 = xp[(size_t)(tid + 256) * 32];
  float s = v0 + v1, s2 = v0 * v0 + v1 * v1;
  for (int off = 32; off; off >>= 1) {
    s  += __shfl_down(s,  off, 64);
    s2 += __shfl_down(s2, off, 64);
  }
  __shared__ float ws1[4], ws2[4];
  __shared__ float mean_s, istd_s;
  int wid = tid >> 6, lane = tid & 63;
  if (lane == 0) { ws1[wid] = s; ws2[wid] = s2; }
  __syncthreads();
  if (tid == 0) {
    float t1 = ws1[0] + ws1[1] + ws1[2] + ws1[3];
    float t2 = ws2[0] + ws2[1] + ws2[2] + ws2[3];
    float mean = t1 / 512.f;
    float var = t2 / 512.f - mean * mean;
    float sd = sqrtf(var + 1e-5f);
    mean_s = mean; istd_s = 1.f / sd;
    stats[row] = mean; stats[512 + row] = sd;
  }
  __syncthreads();
  float w = aw[c], bb = ab[c];
  float m = mean_s, is = istd_s;
  F[(size_t)row * SEQ + tid]       = (v0 - m) * is * w + bb;
  F[(size_t)row * SEQ + tid + 256] = (v1 - m) * is * w + bb;
}

// R0_sc = A_sc^T  (R slot 0 per scale)
__global__ __launch_bounds__(256) void transpose_sq_k(const float* A0, const float* A1,
                                                      const float* A2, float* R) {
  long idx = (long)blockIdx.x * 256 + threadIdx.x;   // 3*65536
  int scl = (int)(idx >> 16);
  int r = (int)(idx & 65535);
  int m = r >> 8, i = r & 255;
  const float* A = scl == 0 ? A0 : (scl == 1 ? A1 : A2);
  R[(size_t)scl * 2 * 65536 + (size_t)m * 256 + i] = A[(size_t)i * 256 + m];
}

__global__ void kryinit_k(const float* B0, const float* B1, const float* B2, float* Kry) {
  int scl = blockIdx.x; int i = threadIdx.x;
  const float* B = scl == 0 ? B0 : (scl == 1 ? B1 : B2);
  Kry[(size_t)scl * 512 * 256 + i] = B[i];
}

// Et_sc[o][p] = E_sc[base+p][o]  (transpose of last-512-rows slice)
__global__ __launch_bounds__(256) void transposeE_k(const float* E0, const float* E1,
                                                    const float* E2, float* Et) {
  long idx = (long)blockIdx.x * 256 + threadIdx.x;   // 3 * 131072
  int scl = (int)(idx / 131072);
  int r = (int)(idx % 131072);
  int p = r >> 8, o = r & 255;
  const float* E; int rows;
  if (scl == 0) { E = E0; rows = 512; }
  else if (scl == 1) { E = E1; rows = 1024; }
  else { E = E2; rows = 2048; }
  int base = rows - 512;
  Et[(size_t)scl * 131072 + (size_t)o * 512 + p] = E[(size_t)(base + p) * 256 + o];
}

// Q[st][i*64 + 2k + {0,1}] = z_k^st * Lambda^{(511-st)}[i,k]
__global__ __launch_bounds__(256) void qbuild_k(const float* __restrict__ Kry_s,
                                                float* __restrict__ Q) {
  int i = blockIdx.x * 8 + (threadIdx.x >> 5);
  int k = threadIdx.x & 31;
  float ar = 0.f, ai = 0.f;
  const float step = 2.f * PI_F / 512.f;
  for (int m = 0; m < 512; m++) {
    float kap = Kry_s[(size_t)m * 256 + i];
    int ph = (k * m) & 511;
    float sn, cn; __sincosf(step * ph, &sn, &cn);
    ar += kap * cn;                 // z^m = cos - i sin
    ai -= kap * sn;
    int st = 511 - m;
    int ph2 = (k * st) & 511;
    float sn2, cn2; __sincosf(step * ph2, &sn2, &cn2);
    float qr = ar * cn2 + ai * sn2; // (ar+i ai)*(cn2 - i sn2)
    float qi = ai * cn2 - ar * sn2;
    size_t base = (size_t)st * KBIG + (size_t)i * 64 + 2 * k;
    *(float2*)&Q[base] = make_float2(qr, qi);
  }
}

// Wbig[(i*64 + 2k + c)][o]:  c=0 -> gamma*(cos w*wr + sin w*wi); c=1 -> gamma*(sin w*wr - cos w*wi)
__global__ __launch_bounds__(256) void wbig_k(const float* __restrict__ wr,
                                              const float* __restrict__ wi,
                                              float* __restrict__ W) {
  int i = blockIdx.x;            // 0..255
  int half = blockIdx.y;         // 0..1
  int o0 = half * 128;
  __shared__ float wrs[128 * 33];
  __shared__ float wis[128 * 33];
  int tid = threadIdx.x;
  const float* wrp = wr + (size_t)i * 8192 + (size_t)o0 * 32;
  const float* wip = wi + (size_t)i * 8192 + (size_t)o0 * 32;
  for (int t = 0; t < 16; t++) {
    int li = t * 256 + tid;      // 0..4095
    int ol = li >> 5, kk = li & 31;
    wrs[ol * 33 + kk] = wrp[li];
    wis[ol * 33 + kk] = wip[li];
  }
  __syncthreads();
  int ol = tid & 127;
  int rh = tid >> 7;             // 0..1
  for (int it = 0; it < 32; it++) {
    int rl = it * 2 + rh;        // 0..63 = 2k + c
    int k = rl >> 1, c = rl & 1;
    float g = (k == 0) ? (1.f / 512.f) : (2.f / 512.f);
    float sn, cn; __sincosf((2.f * PI_F / 512.f) * k, &sn, &cn);
    float a = wrs[ol * 33 + k], b = wis[ol * 33 + k];
    float v = (c == 0) ? g * (cn * a + sn * b) : g * (sn * a - cn * b);
    W[(size_t)(i * 64 + rl) * 256 + o0 + ol] = v;
  }
}

// Final: denorm + channel projection
__global__ __launch_bounds__(256) void final_k(const float* __restrict__ y0,
                                               const float* __restrict__ stats,
                                               const float* __restrict__ aw,
                                               const float* __restrict__ ab,
                                               const float* __restrict__ mlp_b,
                                               const float* __restrict__ pw,
                                               const float* __restrict__ pb,
                                               float* __restrict__ out) {
  int b = blockIdx.y;
  int p0 = blockIdx.x * 8;
  int tid = threadIdx.x;
  __shared__ float ys[32 * 8];
  __shared__ float pws[32 * 32];
  for (int t = tid; t < 1024; t += 256) pws[t] = pw[t];
  int c = tid >> 3, pl = tid & 7;
  int row = b * 32 + c;
  float mean = stats[row], sd = stats[512 + row];
  float raw = y0[(size_t)row * 512 + p0 + pl];
  float v = ((raw + mlp_b[0]) - ab[c]) / (aw[c] + 1e-10f) * sd + mean;
  ys[c * 8 + pl] = v;
  __syncthreads();
  int co = tid & 31; int pl2 = tid >> 5;
  float accv = pb[co];
  #pragma unroll
  for (int cc = 0; cc < 32; cc++) accv += ys[cc * 8 + pl2] * pws[cc * 32 + co];
  out[(size_t)b * 512 * 32 + (size_t)(p0 + pl2) * 32 + co] = accv;
}

// ---------------- launch ----------------

extern "C" void kernel_launch(void* const* d_in, const int* in_sizes, int n_in,
                              void* d_out, int out_size, void* d_ws, size_t ws_size,
                              hipStream_t stream) {
  const float* x_enc = (const float*)d_in[0];
  const float* aw = (const float*)d_in[4];
  const float* ab = (const float*)d_in[5];
  const float* wr[3] = {(const float*)d_in[6], (const float*)d_in[8], (const float*)d_in[10]};
  const float* wi[3] = {(const float*)d_in[7], (const float*)d_in[9], (const float*)d_in[11]};
  const float* mlp_w = (const float*)d_in[12];
  const float* mlp_b = (const float*)d_in[13];
  const float* proj_w = (const float*)d_in[14];
  const float* proj_b = (const float*)d_in[15];
  const float* Am[3]  = {(const float*)d_in[16], (const float*)d_in[19], (const float*)d_in[22]};
  const float* Bv[3]  = {(const float*)d_in[17], (const float*)d_in[20], (const float*)d_in[23]};
  const float* Em[3]  = {(const float*)d_in[18], (const float*)d_in[21], (const float*)d_in[24]};

  float* w = (float*)d_ws;
  float* F     = w; w += 512 * 512;
  float* stats = w; w += 1024;
  float* Kry   = w; w += 3 * 512 * 256;
  float* R     = w; w += 3 * 2 * 65536;
  float* U     = w; w += 3 * 512 * 256;   // U and Ttot contiguous (zeroed together)
  float* Ttot  = w; w += 512 * 512;
  float* Et    = w; w += 3 * 256 * 512;
  float* y0    = w; w += 512 * 512;
  float* Q     = w; w += (size_t)512 * KBIG;
  float* Wb    = w; w += (size_t)KBIG * 256;

  revin_k<<<512, 256, 0, stream>>>(x_enc, aw, ab, F, stats);
  transpose_sq_k<<<768, 256, 0, stream>>>(Am[0], Am[1], Am[2], R);
  kryinit_k<<<3, 256, 0, stream>>>(Bv[0], Bv[1], Bv[2], Kry);
  transposeE_k<<<1536, 256, 0, stream>>>(Em[0], Em[1], Em[2], Et);
  zerobuf_k<<<(3 * 512 * 256 + 512 * 512 + 255) / 256, 256, 0, stream>>>(U, 3 * 512 * 256 + 512 * 512);

  // Krylov doubling: Kry rows [2^j .. 2^(j+1)) = Kry[0..2^j) @ R_j ; R_{j+1} = R_j @ R_j
  for (int j = 0; j < 9; j++) {
    GemmJobs P{};
    int M = 1 << j;
    int cur = j & 1;
    for (int s = 0; s < 3; s++) {
      float* Ks = Kry + (size_t)s * 512 * 256;
      float* Rj = R + (size_t)s * 2 * 65536 + (size_t)cur * 65536;
      float* Rn = R + (size_t)s * 2 * 65536 + (size_t)(1 - cur) * 65536;
      P.j[s] = {Ks, Rj, Ks + (size_t)M * 256, nullptr, M, 256, 256, 0, 256, 0};
      if (j < 8) P.j[3 + s] = {Rj, Rj, Rn, nullptr, 256, 256, 256, 0, 256, 0};
    }
    int nz = (j < 8) ? 6 : 3;
    gemm_k<<<dim3(4, 4, nz), 256, 0, stream>>>(P);
  }

  // Per scale: Q build, Wbig build, U = Q @ Wbig (split-K=16, atomic accumulate)
  for (int s = 0; s < 3; s++) {
    qbuild_k<<<32, 256, 0, stream>>>(Kry + (size_t)s * 512 * 256, Q);
    wbig_k<<<dim3(256, 2), 256, 0, stream>>>(wr[s], wi[s], Wb);
    GemmJobs P{};
    for (int ch = 0; ch < 16; ch++)
      P.j[ch] = {Q, Wb, U + (size_t)s * 512 * 256, nullptr, 512, 256, KBIG,
                 ch * 1024, (ch + 1) * 1024, 1};
    gemm_k<<<dim3(8, 4, 16), 256, 0, stream>>>(P);
  }

  // Ttot += mlp_w[s] * U_s @ Et_s
  {
    GemmJobs P{};
    for (int s = 0; s < 3; s++)
      P.j[s] = {U + (size_t)s * 512 * 256, Et + (size_t)s * 131072, Ttot,
                mlp_w + s, 512, 512, 256, 0, 256, 1};
    gemm_k<<<dim3(8, 8, 3), 256, 0, stream>>>(P);
  }

  // y0 = F @ Ttot
  {
    GemmJobs P{};
    P.j[0] = {F, Ttot, y0, nullptr, 512, 512, 512, 0, 512, 0};
    gemm_k<<<dim3(8, 8, 1), 256, 0, stream>>>(P);
  }

  final_k<<<dim3(64, 16), 256, 0, stream>>>(y0, stats, aw, ab, mlp_b, proj_w, proj_b,
                                            (float*)d_out);
}

// Round 2
// 605.836 us; speedup vs baseline: 1.5877x; 1.5877x over previous
//
#include <hip/hip_runtime.h>
#include <math.h>

#define SEQ 512
#define NORD 256
#define MODES 32
#define KBIG (NORD*MODES*2)   // 16384
#define PI_F 3.14159265358979323846f

typedef _Float16 half8 __attribute__((ext_vector_type(8)));
typedef float floatx4 __attribute__((ext_vector_type(4)));

// ---------------- generic job-based f32 GEMM (64x64 tile, 256 thr, 4x4 micro) ----

struct GemmJob {
  const float* A; const float* B; float* C; const float* scale_ptr;
  int M, N, lda, k0, k1, atomic;
};
struct GemmJobs { GemmJob j[16]; };

__global__ __launch_bounds__(256) void gemm_k(GemmJobs P) {
  GemmJob jb = P.j[blockIdx.z];
  int row0 = blockIdx.x * 64, col0 = blockIdx.y * 64;
  if (row0 >= jb.M || col0 >= jb.N) return;
  __shared__ __align__(16) float As[16][68];
  __shared__ __align__(16) float Bs[16][68];
  int tid = threadIdx.x;
  int tx = tid & 15, ty = tid >> 4;
  float acc[4][4] = {{0.f}};
  const float* A = jb.A; const float* B = jb.B;
  int M = jb.M, N = jb.N, lda = jb.lda;
  for (int kb = jb.k0; kb < jb.k1; kb += 16) {
    #pragma unroll
    for (int rr = 0; rr < 4; rr++) {
      int r = ty + rr * 16;
      int gr = row0 + r;
      float v = 0.f;
      if (gr < M) v = A[(size_t)gr * lda + kb + tx];
      As[tx][r] = v;
    }
    #pragma unroll
    for (int rr = 0; rr < 4; rr++) {
      int kk = (tid >> 6) + rr * 4;
      int cc = tid & 63;
      Bs[kk][cc] = B[(size_t)(kb + kk) * N + col0 + cc];
    }
    __syncthreads();
    #pragma unroll
    for (int kk = 0; kk < 16; kk++) {
      float4 a = *(const float4*)&As[kk][ty * 4];
      float4 b = *(const float4*)&Bs[kk][tx * 4];
      acc[0][0] += a.x*b.x; acc[0][1] += a.x*b.y; acc[0][2] += a.x*b.z; acc[0][3] += a.x*b.w;
      acc[1][0] += a.y*b.x; acc[1][1] += a.y*b.y; acc[1][2] += a.y*b.z; acc[1][3] += a.y*b.w;
      acc[2][0] += a.z*b.x; acc[2][1] += a.z*b.y; acc[2][2] += a.z*b.z; acc[2][3] += a.z*b.w;
      acc[3][0] += a.w*b.x; acc[3][1] += a.w*b.y; acc[3][2] += a.w*b.z; acc[3][3] += a.w*b.w;
    }
    __syncthreads();
  }
  float sc = jb.scale_ptr ? *jb.scale_ptr : 1.f;
  int r0 = row0 + ty * 4, c0 = col0 + tx * 4;
  #pragma unroll
  for (int i = 0; i < 4; i++) {
    int gr = r0 + i;
    if (gr < M) {
      #pragma unroll
      for (int jjj = 0; jjj < 4; jjj++) {
        float v = acc[i][jjj] * sc;
        if (jb.atomic) atomicAdd(&jb.C[(size_t)gr * N + c0 + jjj], v);
        else jb.C[(size_t)gr * N + c0 + jjj] = v;
      }
    }
  }
}

// ---------------- merged prep: transposes + kry init + zeroing ----------------

__global__ __launch_bounds__(256) void prep_k(const float* A0, const float* A1, const float* A2,
                                              const float* B0, const float* B1, const float* B2,
                                              const float* E0, const float* E1, const float* E2,
                                              float* R, float* Kry, float* Et, float* Z) {
  long bid = blockIdx.x;
  if (bid < 768) {
    long idx = bid * 256 + threadIdx.x;
    int scl = (int)(idx >> 16);
    int r = (int)(idx & 65535);
    int m = r >> 8, i2 = r & 255;
    const float* A = scl == 0 ? A0 : (scl == 1 ? A1 : A2);
    R[(size_t)scl * 2 * 65536 + (size_t)m * 256 + i2] = A[(size_t)i2 * 256 + m];
  } else if (bid < 2304) {
    long idx = (bid - 768) * 256 + threadIdx.x;
    int scl = (int)(idx / 131072);
    int r = (int)(idx % 131072);
    int p = r >> 8, o = r & 255;
    const float* E; int rows;
    if (scl == 0) { E = E0; rows = 512; }
    else if (scl == 1) { E = E1; rows = 1024; }
    else { E = E2; rows = 2048; }
    int base = rows - 512;
    Et[(size_t)scl * 131072 + (size_t)o * 512 + p] = E[(size_t)(base + p) * 256 + o];
  } else if (bid < 2307) {
    int scl = (int)(bid - 2304);
    const float* B = scl == 0 ? B0 : (scl == 1 ? B1 : B2);
    Kry[(size_t)scl * 512 * 256 + threadIdx.x] = B[threadIdx.x];
  } else {
    long idx = (bid - 2307) * 256 + threadIdx.x;
    if (idx < 655360) Z[idx] = 0.f;
  }
}

// ---------------- RevIN ----------------

__global__ __launch_bounds__(256) void revin_k(const float* __restrict__ x,
                                               const float* __restrict__ aw,
                                               const float* __restrict__ ab,
                                               float* __restrict__ F,
                                               float* __restrict__ stats) {
  int row = blockIdx.x;            // b*32 + c
  int b = row >> 5, c = row & 31;
  int tid = threadIdx.x;
  const float* xp = x + (size_t)b * SEQ * 32 + c;
  float v0 = xp[(size_t)tid * 32];
  float v1 = xp[(size_t)(tid + 256) * 32];
  float s = v0 + v1, s2 = v0 * v0 + v1 * v1;
  for (int off = 32; off; off >>= 1) {
    s  += __shfl_down(s,  off, 64);
    s2 += __shfl_down(s2, off, 64);
  }
  __shared__ float ws1[4], ws2[4];
  __shared__ float mean_s, istd_s;
  int wid = tid >> 6, lane = tid & 63;
  if (lane == 0) { ws1[wid] = s; ws2[wid] = s2; }
  __syncthreads();
  if (tid == 0) {
    float t1 = ws1[0] + ws1[1] + ws1[2] + ws1[3];
    float t2 = ws2[0] + ws2[1] + ws2[2] + ws2[3];
    float mean = t1 / 512.f;
    float var = t2 / 512.f - mean * mean;
    float sd = sqrtf(var + 1e-5f);
    mean_s = mean; istd_s = 1.f / sd;
    stats[row] = mean; stats[512 + row] = sd;
  }
  __syncthreads();
  float w = aw[c], bb = ab[c];
  float m = mean_s, is = istd_s;
  F[(size_t)row * SEQ + tid]       = (v0 - m) * is * w + bb;
  F[(size_t)row * SEQ + tid + 256] = (v1 - m) * is * w + bb;
}

// ---------------- qbuild: 2-phase chunked prefix over m ----------------
// Phase A: chunk partials P[c][k][i] = sum_{m in chunk} z_k^m kappa_m[i]

__global__ __launch_bounds__(256) void qbuildA_k(const float* __restrict__ Kry_s,
                                                 float2* __restrict__ P) {
  int k = blockIdx.x & 31, c = blockIdx.x >> 5;
  int i = threadIdx.x;
  float ar = 0.f, ai = 0.f;
  const float step = 2.f * PI_F / 512.f;
  int m0 = c * 64;
  for (int mm = 0; mm < 64; mm++) {
    int m = m0 + mm;
    float kap = Kry_s[(size_t)m * 256 + i];
    float sn, cn; __sincosf(step * (float)((k * m) & 511), &sn, &cn);
    ar += kap * cn; ai -= kap * sn;
  }
  P[(size_t)(c * 32 + k) * 256 + i] = make_float2(ar, ai);
}

// Phase B: within-chunk running prefix + z^st twiddle, f16 output via LDS transpose.
// Q layout: [st][kg] halves, kg = i*64 + 2k + {re,im}, row-major (k-contiguous 16B chunks).

__global__ __launch_bounds__(256) void qbuildB_k(const float* __restrict__ Kry_s,
                                                 const float2* __restrict__ P,
                                                 _Float16* __restrict__ Qf) {
  int ig = blockIdx.x & 31, c = blockIdx.x >> 5;   // ig: group of 8 i's
  int tid = threadIdx.x;
  int k = tid & 31, il = tid >> 5;                 // il 0..7
  int i = ig * 8 + il;
  __shared__ __align__(16) unsigned int buf[16 * 256];  // 16 st-rows x 1KB
  float ar = 0.f, ai = 0.f;
  for (int cp = 0; cp < c; cp++) {
    float2 p = P[(size_t)(cp * 32 + k) * 256 + i];
    ar += p.x; ai += p.y;
  }
  const float step = 2.f * PI_F / 512.f;
  int m0 = c * 64;
  unsigned int* Qd = (unsigned int*)Qf;
  for (int mb = 0; mb < 64; mb += 16) {
    #pragma unroll
    for (int mm = 0; mm < 16; mm++) {
      int m = m0 + mb + mm;
      float kap = Kry_s[(size_t)m * 256 + i];
      float sn, cn; __sincosf(step * (float)((k * m) & 511), &sn, &cn);
      ar += kap * cn; ai -= kap * sn;
      int st = 511 - m;
      float sn2, cn2; __sincosf(step * (float)((k * st) & 511), &sn2, &cn2);
      float qr = ar * cn2 + ai * sn2;
      float qi = ai * cn2 - ar * sn2;
      qr = fminf(fmaxf(qr, -60000.f), 60000.f);
      qi = fminf(fmaxf(qi, -60000.f), 60000.f);
      _Float16 h0 = (_Float16)qr, h1 = (_Float16)qi;
      unsigned short u0, u1;
      __builtin_memcpy(&u0, &h0, 2); __builtin_memcpy(&u1, &h1, 2);
      buf[(st & 15) * 256 + il * 32 + k] = (unsigned int)u0 | ((unsigned int)u1 << 16);
    }
    __syncthreads();
    int st_hi = 511 - (m0 + mb);   // st values this batch: st_hi-15 .. st_hi
    #pragma unroll
    for (int p = 0; p < 4; p++) {
      int idx = p * 256 + tid;
      int r = idx >> 6, part = idx & 63;
      int st = st_hi - 15 + r;
      uint4 v = *(uint4*)&buf[(st & 15) * 256 + part * 4];
      *(uint4*)&Qd[(size_t)st * 8192 + (size_t)ig * 256 + part * 4] = v;
    }
    __syncthreads();
  }
}

// ---------------- Wbig^T build (f16, x4096 scale): Wt[o][kg] ----------------

__global__ __launch_bounds__(256) void wbigT_k(const float* __restrict__ wr,
                                               const float* __restrict__ wi,
                                               _Float16* __restrict__ Wt) {
  int og = blockIdx.x & 31, iq = blockIdx.x >> 5;   // 32 o-groups x 8 i-quarters
  int tid = threadIdx.x;
  int ol = tid >> 5, k = tid & 31;
  int o = og * 8 + ol;
  float sn, cn; __sincosf((2.f * PI_F / 512.f) * (float)k, &sn, &cn);
  float g = ((k == 0) ? (1.f / 512.f) : (2.f / 512.f)) * 4096.f;
  float gc = g * cn, gs = g * sn;
  unsigned int* Wd = (unsigned int*)Wt;
  for (int ii = 0; ii < 32; ii++) {
    int i = iq * 32 + ii;
    float a = wr[(size_t)i * 8192 + o * 32 + k];
    float b = wi[(size_t)i * 8192 + o * 32 + k];
    float v0 = gc * a + gs * b;
    float v1 = gs * a - gc * b;
    _Float16 h0 = (_Float16)v0, h1 = (_Float16)v1;
    unsigned short u0, u1;
    __builtin_memcpy(&u0, &h0, 2); __builtin_memcpy(&u1, &h1, 2);
    Wd[(size_t)o * 8192 + (size_t)i * 32 + k] = (unsigned int)u0 | ((unsigned int)u1 << 16);
  }
}

// ---------------- U = Q @ Wb via f16 MFMA, split-K atomics ----------------
// BM=128, BN=128, BK=64, grid (4, 2, 32). LDS in fragment-permuted layout.

__global__ __launch_bounds__(256) void umfma_k(const _Float16* __restrict__ Qf,
                                               const _Float16* __restrict__ Wt,
                                               float* __restrict__ U) {
  __shared__ __align__(16) _Float16 Al[8192];
  __shared__ __align__(16) _Float16 Bl[8192];
  int m0 = blockIdx.x * 128;
  int n0 = blockIdx.y * 128;
  int kb0 = blockIdx.z * 512;
  int tid = threadIdx.x;
  int w = tid >> 6, lane = tid & 63;
  int quad = lane >> 4, lm = lane & 15;
  floatx4 acc[4][4];
  #pragma unroll
  for (int a = 0; a < 4; a++)
    #pragma unroll
    for (int b = 0; b < 4; b++) acc[a][b] = (floatx4)(0.f);
  int wm = (w & 1) * 64, wn = (w >> 1) * 64;
  for (int kb = kb0; kb < kb0 + 512; kb += 64) {
    __syncthreads();
    #pragma unroll
    for (int p = 0; p < 4; p++) {
      int idx = p * 256 + tid;
      int row = idx >> 3, kc = idx & 7;
      int slot = ((kc >> 2) * 8 + (row >> 4)) * 64 + (kc & 3) * 16 + (row & 15);
      *(half8*)&Al[slot * 8] = *(const half8*)&Qf[(size_t)(m0 + row) * 16384 + kb + kc * 8];
      *(half8*)&Bl[slot * 8] = *(const half8*)&Wt[(size_t)(n0 + row) * 16384 + kb + kc * 8];
    }
    __syncthreads();
    #pragma unroll
    for (int ks = 0; ks < 2; ks++) {
      half8 af[4], bf[4];
      #pragma unroll
      for (int t = 0; t < 4; t++) {
        int mt = (wm >> 4) + t;
        af[t] = *(half8*)&Al[((ks * 8 + mt) * 64 + quad * 16 + lm) * 8];
        int nt = (wn >> 4) + t;
        bf[t] = *(half8*)&Bl[((ks * 8 + nt) * 64 + quad * 16 + lm) * 8];
      }
      #pragma unroll
      for (int mi = 0; mi < 4; mi++)
        #pragma unroll
        for (int ni = 0; ni < 4; ni++)
          acc[mi][ni] = __builtin_amdgcn_mfma_f32_16x16x32_f16(af[mi], bf[ni], acc[mi][ni], 0, 0, 0);
    }
  }
  #pragma unroll
  for (int mi = 0; mi < 4; mi++) {
    int gr0 = m0 + wm + mi * 16 + quad * 4;
    #pragma unroll
    for (int ni = 0; ni < 4; ni++) {
      int gc = n0 + wn + ni * 16 + lm;
      #pragma unroll
      for (int r = 0; r < 4; r++)
        atomicAdd(&U[(size_t)(gr0 + r) * 256 + gc], acc[mi][ni][r] * (1.f / 4096.f));
    }
  }
}

// ---------------- Final: denorm + channel projection ----------------

__global__ __launch_bounds__(256) void final_k(const float* __restrict__ y0,
                                               const float* __restrict__ stats,
                                               const float* __restrict__ aw,
                                               const float* __restrict__ ab,
                                               const float* __restrict__ mlp_b,
                                               const float* __restrict__ pw,
                                               const float* __restrict__ pb,
                                               float* __restrict__ out) {
  int b = blockIdx.y;
  int p0 = blockIdx.x * 8;
  int tid = threadIdx.x;
  __shared__ float ys[32 * 8];
  __shared__ float pws[32 * 32];
  for (int t = tid; t < 1024; t += 256) pws[t] = pw[t];
  int c = tid >> 3, pl = tid & 7;
  int row = b * 32 + c;
  float mean = stats[row], sd = stats[512 + row];
  float raw = y0[(size_t)row * 512 + p0 + pl];
  float v = ((raw + mlp_b[0]) - ab[c]) / (aw[c] + 1e-10f) * sd + mean;
  ys[c * 8 + pl] = v;
  __syncthreads();
  int co = tid & 31; int pl2 = tid >> 5;
  float accv = pb[co];
  #pragma unroll
  for (int cc = 0; cc < 32; cc++) accv += ys[cc * 8 + pl2] * pws[cc * 32 + co];
  out[(size_t)b * 512 * 32 + (size_t)(p0 + pl2) * 32 + co] = accv;
}

// ---------------- launch ----------------

extern "C" void kernel_launch(void* const* d_in, const int* in_sizes, int n_in,
                              void* d_out, int out_size, void* d_ws, size_t ws_size,
                              hipStream_t stream) {
  const float* x_enc = (const float*)d_in[0];
  const float* aw = (const float*)d_in[4];
  const float* ab = (const float*)d_in[5];
  const float* wr[3] = {(const float*)d_in[6], (const float*)d_in[8], (const float*)d_in[10]};
  const float* wi[3] = {(const float*)d_in[7], (const float*)d_in[9], (const float*)d_in[11]};
  const float* mlp_w = (const float*)d_in[12];
  const float* mlp_b = (const float*)d_in[13];
  const float* proj_w = (const float*)d_in[14];
  const float* proj_b = (const float*)d_in[15];
  const float* Am[3]  = {(const float*)d_in[16], (const float*)d_in[19], (const float*)d_in[22]};
  const float* Bv[3]  = {(const float*)d_in[17], (const float*)d_in[20], (const float*)d_in[23]};
  const float* Em[3]  = {(const float*)d_in[18], (const float*)d_in[21], (const float*)d_in[24]};

  float* w = (float*)d_ws;
  float* F     = w; w += 512 * 512;
  float* stats = w; w += 1024;
  float* Kry   = w; w += 3 * 512 * 256;
  float* R     = w; w += 3 * 2 * 65536;
  float* U     = w; w += 3 * 512 * 256;   // U and Ttot contiguous (zeroed together)
  float* Ttot  = w; w += 512 * 512;
  float* Et    = w; w += 3 * 256 * 512;
  float* y0    = w; w += 512 * 512;
  float* Pp    = w; w += 8 * 32 * 256 * 2;
  _Float16* Qf = (_Float16*)w; w += (size_t)512 * KBIG / 2;
  _Float16* Wb = (_Float16*)w; w += (size_t)KBIG * 256 / 2;

  revin_k<<<512, 256, 0, stream>>>(x_enc, aw, ab, F, stats);
  prep_k<<<4867, 256, 0, stream>>>(Am[0], Am[1], Am[2], Bv[0], Bv[1], Bv[2],
                                   Em[0], Em[1], Em[2], R, Kry, Et, U);

  // Krylov doubling: Kry rows [2^j .. 2^(j+1)) = Kry[0..2^j) @ R_j ; R_{j+1} = R_j @ R_j
  for (int j = 0; j < 9; j++) {
    GemmJobs P{};
    int M = 1 << j;
    int cur = j & 1;
    for (int s = 0; s < 3; s++) {
      float* Ks = Kry + (size_t)s * 512 * 256;
      float* Rj = R + (size_t)s * 2 * 65536 + (size_t)cur * 65536;
      float* Rn = R + (size_t)s * 2 * 65536 + (size_t)(1 - cur) * 65536;
      P.j[s] = {Ks, Rj, Ks + (size_t)M * 256, nullptr, M, 256, 256, 0, 256, 0};
      if (j < 8) P.j[3 + s] = {Rj, Rj, Rn, nullptr, 256, 256, 256, 0, 256, 0};
    }
    int nz = (j < 8) ? 6 : 3;
    gemm_k<<<dim3(4, 4, nz), 256, 0, stream>>>(P);
  }

  // Per scale: Q build (2-phase), WbT build, U = Q @ Wb via MFMA (split-K 32, atomics)
  for (int s = 0; s < 3; s++) {
    const float* Ks = Kry + (size_t)s * 512 * 256;
    qbuildA_k<<<256, 256, 0, stream>>>(Ks, (float2*)Pp);
    qbuildB_k<<<256, 256, 0, stream>>>(Ks, (const float2*)Pp, Qf);
    wbigT_k<<<256, 256, 0, stream>>>(wr[s], wi[s], Wb);
    umfma_k<<<dim3(4, 2, 32), 256, 0, stream>>>(Qf, Wb, U + (size_t)s * 512 * 256);
  }

  // Ttot += mlp_w[s] * U_s @ Et_s
  {
    GemmJobs P{};
    for (int s = 0; s < 3; s++)
      P.j[s] = {U + (size_t)s * 512 * 256, Et + (size_t)s * 131072, Ttot,
                mlp_w + s, 512, 512, 256, 0, 256, 1};
    gemm_k<<<dim3(8, 8, 3), 256, 0, stream>>>(P);
  }

  // y0 = F @ Ttot
  {
    GemmJobs P{};
    P.j[0] = {F, Ttot, y0, nullptr, 512, 512, 512, 0, 512, 0};
    gemm_k<<<dim3(8, 8, 1), 256, 0, stream>>>(P);
  }

  final_k<<<dim3(64, 16), 256, 0, stream>>>(y0, stats, aw, ab, mlp_b, proj_w, proj_b,
                                            (float*)d_out);
}

// Round 3
// 373.191 us; speedup vs baseline: 2.5775x; 1.6234x over previous
//
#include <hip/hip_runtime.h>
#include <math.h>

#define SEQ 512
#define NORD 256
#define MODES 32
#define KBIG (NORD*MODES*2)   // 16384
#define PI_F 3.14159265358979323846f

typedef _Float16 half8 __attribute__((ext_vector_type(8)));
typedef float floatx4 __attribute__((ext_vector_type(4)));

// ---------------- latency-tolerant f32 GEMM: 32x32 tile, BK=64, reg prefetch ----

struct GJob {
  const float* A; const float* B; float* C; const float* scale_ptr;
  int M, N, lda, k0, k1, atomic;
};
struct GJobs { GJob j[6]; };

__global__ __launch_bounds__(256) void gemm32_k(GJobs P) {
  GJob jb = P.j[blockIdx.z];
  int col0 = blockIdx.x * 32;
  int row0 = blockIdx.y * 32;
  if (row0 >= jb.M || col0 >= jb.N) return;
  __shared__ float As[64][34];   // [k][m]; pad 34 keeps b64 reads aligned, 4-way store conflicts only
  __shared__ float Bs[64][36];   // [k][n]; pad 36 keeps float4 stores 16B-aligned
  int tid = threadIdx.x;
  int tx = tid & 15, ty = tid >> 4;
  const float* A = jb.A; const float* B = jb.B;
  int M = jb.M, N = jb.N, lda = jb.lda;
  int kcA = (tid & 15) * 4, rA = tid >> 4;
  int ccB = (tid & 7) * 4, kkB = tid >> 3;
  int gr0 = row0 + rA, gr1 = row0 + rA + 16;
  const float4 z4 = make_float4(0.f, 0.f, 0.f, 0.f);
  float4 a0, a1, b0, b1;
  {
    int kb = jb.k0;
    a0 = (gr0 < M) ? *(const float4*)&A[(size_t)gr0 * lda + kb + kcA] : z4;
    a1 = (gr1 < M) ? *(const float4*)&A[(size_t)gr1 * lda + kb + kcA] : z4;
    b0 = *(const float4*)&B[(size_t)(kb + kkB) * N + col0 + ccB];
    b1 = *(const float4*)&B[(size_t)(kb + kkB + 32) * N + col0 + ccB];
  }
  float acc00 = 0.f, acc01 = 0.f, acc10 = 0.f, acc11 = 0.f;
  for (int kb = jb.k0; kb < jb.k1; kb += 64) {
    As[kcA+0][rA] = a0.x; As[kcA+1][rA] = a0.y; As[kcA+2][rA] = a0.z; As[kcA+3][rA] = a0.w;
    As[kcA+0][rA+16] = a1.x; As[kcA+1][rA+16] = a1.y; As[kcA+2][rA+16] = a1.z; As[kcA+3][rA+16] = a1.w;
    *(float4*)&Bs[kkB][ccB] = b0;
    *(float4*)&Bs[kkB+32][ccB] = b1;
    __syncthreads();
    if (kb + 64 < jb.k1) {
      int kn = kb + 64;
      a0 = (gr0 < M) ? *(const float4*)&A[(size_t)gr0 * lda + kn + kcA] : z4;
      a1 = (gr1 < M) ? *(const float4*)&A[(size_t)gr1 * lda + kn + kcA] : z4;
      b0 = *(const float4*)&B[(size_t)(kn + kkB) * N + col0 + ccB];
      b1 = *(const float4*)&B[(size_t)(kn + kkB + 32) * N + col0 + ccB];
    }
    #pragma unroll
    for (int k = 0; k < 64; k++) {
      float2 av = *(float2*)&As[k][ty * 2];
      float2 bv = *(float2*)&Bs[k][tx * 2];
      acc00 += av.x * bv.x; acc01 += av.x * bv.y;
      acc10 += av.y * bv.x; acc11 += av.y * bv.y;
    }
    __syncthreads();
  }
  float sc = jb.scale_ptr ? *jb.scale_ptr : 1.f;
  int gr = row0 + ty * 2, gc = col0 + tx * 2;
  float v00 = acc00 * sc, v01 = acc01 * sc, v10 = acc10 * sc, v11 = acc11 * sc;
  if (jb.atomic) {
    if (gr < M)     { atomicAdd(&jb.C[(size_t)gr * N + gc], v00);     atomicAdd(&jb.C[(size_t)gr * N + gc + 1], v01); }
    if (gr + 1 < M) { atomicAdd(&jb.C[(size_t)(gr+1) * N + gc], v10); atomicAdd(&jb.C[(size_t)(gr+1) * N + gc + 1], v11); }
  } else {
    if (gr < M)     { jb.C[(size_t)gr * N + gc] = v00;     jb.C[(size_t)gr * N + gc + 1] = v01; }
    if (gr + 1 < M) { jb.C[(size_t)(gr+1) * N + gc] = v10; jb.C[(size_t)(gr+1) * N + gc + 1] = v11; }
  }
}

// ---------------- merged prep: transposes + kry init + zeroing ----------------

__global__ __launch_bounds__(256) void prep_k(const float* A0, const float* A1, const float* A2,
                                              const float* B0, const float* B1, const float* B2,
                                              const float* E0, const float* E1, const float* E2,
                                              float* R, float* Kry, float* Et, float* Z) {
  long bid = blockIdx.x;
  if (bid < 768) {
    long idx = bid * 256 + threadIdx.x;
    int scl = (int)(idx >> 16);
    int r = (int)(idx & 65535);
    int m = r >> 8, i2 = r & 255;
    const float* A = scl == 0 ? A0 : (scl == 1 ? A1 : A2);
    R[(size_t)scl * 2 * 65536 + (size_t)m * 256 + i2] = A[(size_t)i2 * 256 + m];
  } else if (bid < 2304) {
    long idx = (bid - 768) * 256 + threadIdx.x;
    int scl = (int)(idx / 131072);
    int r = (int)(idx % 131072);
    int p = r >> 8, o = r & 255;
    const float* E; int rows;
    if (scl == 0) { E = E0; rows = 512; }
    else if (scl == 1) { E = E1; rows = 1024; }
    else { E = E2; rows = 2048; }
    int base = rows - 512;
    Et[(size_t)scl * 131072 + (size_t)o * 512 + p] = E[(size_t)(base + p) * 256 + o];
  } else if (bid < 2307) {
    int scl = (int)(bid - 2304);
    const float* B = scl == 0 ? B0 : (scl == 1 ? B1 : B2);
    Kry[(size_t)scl * 512 * 256 + threadIdx.x] = B[threadIdx.x];
  } else {
    long idx = (bid - 2307) * 256 + threadIdx.x;
    if (idx < 655360) Z[idx] = 0.f;
  }
}

// ---------------- RevIN ----------------

__global__ __launch_bounds__(256) void revin_k(const float* __restrict__ x,
                                               const float* __restrict__ aw,
                                               const float* __restrict__ ab,
                                               float* __restrict__ F,
                                               float* __restrict__ stats) {
  int row = blockIdx.x;            // b*32 + c
  int b = row >> 5, c = row & 31;
  int tid = threadIdx.x;
  const float* xp = x + (size_t)b * SEQ * 32 + c;
  float v0 = xp[(size_t)tid * 32];
  float v1 = xp[(size_t)(tid + 256) * 32];
  float s = v0 + v1, s2 = v0 * v0 + v1 * v1;
  for (int off = 32; off; off >>= 1) {
    s  += __shfl_down(s,  off, 64);
    s2 += __shfl_down(s2, off, 64);
  }
  __shared__ float ws1[4], ws2[4];
  __shared__ float mean_s, istd_s;
  int wid = tid >> 6, lane = tid & 63;
  if (lane == 0) { ws1[wid] = s; ws2[wid] = s2; }
  __syncthreads();
  if (tid == 0) {
    float t1 = ws1[0] + ws1[1] + ws1[2] + ws1[3];
    float t2 = ws2[0] + ws2[1] + ws2[2] + ws2[3];
    float mean = t1 / 512.f;
    float var = t2 / 512.f - mean * mean;
    float sd = sqrtf(var + 1e-5f);
    mean_s = mean; istd_s = 1.f / sd;
    stats[row] = mean; stats[512 + row] = sd;
  }
  __syncthreads();
  float w = aw[c], bb = ab[c];
  float m = mean_s, is = istd_s;
  F[(size_t)row * SEQ + tid]       = (v0 - m) * is * w + bb;
  F[(size_t)row * SEQ + tid + 256] = (v1 - m) * is * w + bb;
}

// ---------------- qbuild: 2-phase chunked prefix over m (batched over scales) ----

__global__ __launch_bounds__(256) void qbuildA_k(const float* __restrict__ Kry,
                                                 float2* __restrict__ Pp, int s0) {
  int bg = blockIdx.x;
  int s = s0 + (bg >> 8);
  int r = bg & 255;
  int k = r & 31, c = r >> 5;
  const float* Kry_s = Kry + (size_t)s * 131072;
  float2* P = Pp + (size_t)s * 65536;
  int i = threadIdx.x;
  float ar = 0.f, ai = 0.f;
  const float step = 2.f * PI_F / 512.f;
  int m0 = c * 64;
  for (int mm = 0; mm < 64; mm++) {
    int m = m0 + mm;
    float kap = Kry_s[(size_t)m * 256 + i];
    float sn, cn; __sincosf(step * (float)((k * m) & 511), &sn, &cn);
    ar += kap * cn; ai -= kap * sn;
  }
  P[(size_t)(c * 32 + k) * 256 + i] = make_float2(ar, ai);
}

__global__ __launch_bounds__(256) void qbuildB_k(const float* __restrict__ Kry,
                                                 const float2* __restrict__ Pp,
                                                 _Float16* __restrict__ Qf, int s0) {
  int bg = blockIdx.x;
  int slab = bg >> 8;
  int s = s0 + slab;
  int r = bg & 255;
  int ig = r & 31, c = r >> 5;
  const float* Kry_s = Kry + (size_t)s * 131072;
  const float2* P = Pp + (size_t)s * 65536;
  unsigned int* Qd = (unsigned int*)(Qf + (size_t)slab * 8388608);
  int tid = threadIdx.x;
  int k = tid & 31, il = tid >> 5;
  int i = ig * 8 + il;
  __shared__ __align__(16) unsigned int buf[16 * 256];
  float ar = 0.f, ai = 0.f;
  for (int cp = 0; cp < c; cp++) {
    float2 p = P[(size_t)(cp * 32 + k) * 256 + i];
    ar += p.x; ai += p.y;
  }
  const float step = 2.f * PI_F / 512.f;
  int m0 = c * 64;
  for (int mb = 0; mb < 64; mb += 16) {
    #pragma unroll
    for (int mm = 0; mm < 16; mm++) {
      int m = m0 + mb + mm;
      float kap = Kry_s[(size_t)m * 256 + i];
      float sn, cn; __sincosf(step * (float)((k * m) & 511), &sn, &cn);
      ar += kap * cn; ai -= kap * sn;
      int st = 511 - m;
      float sn2, cn2; __sincosf(step * (float)((k * st) & 511), &sn2, &cn2);
      float qr = ar * cn2 + ai * sn2;
      float qi = ai * cn2 - ar * sn2;
      qr = fminf(fmaxf(qr, -60000.f), 60000.f);
      qi = fminf(fmaxf(qi, -60000.f), 60000.f);
      _Float16 h0 = (_Float16)qr, h1 = (_Float16)qi;
      unsigned short u0, u1;
      __builtin_memcpy(&u0, &h0, 2); __builtin_memcpy(&u1, &h1, 2);
      buf[(st & 15) * 256 + il * 32 + k] = (unsigned int)u0 | ((unsigned int)u1 << 16);
    }
    __syncthreads();
    int st_hi = 511 - (m0 + mb);
    #pragma unroll
    for (int p = 0; p < 4; p++) {
      int idx = p * 256 + tid;
      int rr = idx >> 6, part = idx & 63;
      int st = st_hi - 15 + rr;
      uint4 v = *(uint4*)&buf[(st & 15) * 256 + part * 4];
      *(uint4*)&Qd[(size_t)st * 8192 + (size_t)ig * 256 + part * 4] = v;
    }
    __syncthreads();
  }
}

// ---------------- Wbig^T build (f16, x4096 scale), batched over scales ----------

__global__ __launch_bounds__(256) void wbigT_k(const float* wr0, const float* wi0,
                                               const float* wr1, const float* wi1,
                                               const float* wr2, const float* wi2,
                                               _Float16* __restrict__ Wt, int s0) {
  int bg = blockIdx.x;
  int slab = bg >> 8;
  int s = s0 + slab;
  int r = bg & 255;
  int og = r & 31, iq = r >> 5;
  const float* wr = s == 0 ? wr0 : (s == 1 ? wr1 : wr2);
  const float* wi = s == 0 ? wi0 : (s == 1 ? wi1 : wi2);
  unsigned int* Wd = (unsigned int*)(Wt + (size_t)slab * 4194304);
  int tid = threadIdx.x;
  int ol = tid >> 5, k = tid & 31;
  int o = og * 8 + ol;
  float sn, cn; __sincosf((2.f * PI_F / 512.f) * (float)k, &sn, &cn);
  float g = ((k == 0) ? (1.f / 512.f) : (2.f / 512.f)) * 4096.f;
  float gc = g * cn, gs = g * sn;
  for (int ii = 0; ii < 32; ii++) {
    int i = iq * 32 + ii;
    float a = wr[(size_t)i * 8192 + o * 32 + k];
    float b = wi[(size_t)i * 8192 + o * 32 + k];
    float v0 = gc * a + gs * b;
    float v1 = gs * a - gc * b;
    _Float16 h0 = (_Float16)v0, h1 = (_Float16)v1;
    unsigned short u0, u1;
    __builtin_memcpy(&u0, &h0, 2); __builtin_memcpy(&u1, &h1, 2);
    Wd[(size_t)o * 8192 + (size_t)i * 32 + k] = (unsigned int)u0 | ((unsigned int)u1 << 16);
  }
}

// ---------------- U = Q @ Wb via f16 MFMA, split-K=16 atomics, batched ----------

__global__ __launch_bounds__(256) void umfma_k(const _Float16* __restrict__ Qf,
                                               const _Float16* __restrict__ Wt,
                                               float* __restrict__ U, int s0) {
  __shared__ __align__(16) _Float16 Al[8192];
  __shared__ __align__(16) _Float16 Bl[8192];
  int slab = blockIdx.z >> 4;
  int kslab = blockIdx.z & 15;
  int s = s0 + slab;
  const _Float16* Q = Qf + (size_t)slab * 8388608;
  const _Float16* W = Wt + (size_t)slab * 4194304;
  float* Us = U + (size_t)s * 131072;
  int m0 = blockIdx.x * 128;
  int n0 = blockIdx.y * 128;
  int kb0 = kslab * 1024;
  int tid = threadIdx.x;
  int w = tid >> 6, lane = tid & 63;
  int quad = lane >> 4, lm = lane & 15;
  floatx4 acc[4][4];
  #pragma unroll
  for (int a = 0; a < 4; a++)
    #pragma unroll
    for (int b = 0; b < 4; b++) acc[a][b] = (floatx4)(0.f);
  int wm = (w & 1) * 64, wn = (w >> 1) * 64;
  for (int kb = kb0; kb < kb0 + 1024; kb += 64) {
    __syncthreads();
    #pragma unroll
    for (int p = 0; p < 4; p++) {
      int idx = p * 256 + tid;
      int row = idx >> 3, kc = idx & 7;
      int slot = ((kc >> 2) * 8 + (row >> 4)) * 64 + (kc & 3) * 16 + (row & 15);
      *(half8*)&Al[slot * 8] = *(const half8*)&Q[(size_t)(m0 + row) * 16384 + kb + kc * 8];
      *(half8*)&Bl[slot * 8] = *(const half8*)&W[(size_t)(n0 + row) * 16384 + kb + kc * 8];
    }
    __syncthreads();
    #pragma unroll
    for (int ks = 0; ks < 2; ks++) {
      half8 af[4], bf[4];
      #pragma unroll
      for (int t = 0; t < 4; t++) {
        int mt = (wm >> 4) + t;
        af[t] = *(half8*)&Al[((ks * 8 + mt) * 64 + quad * 16 + lm) * 8];
        int nt = (wn >> 4) + t;
        bf[t] = *(half8*)&Bl[((ks * 8 + nt) * 64 + quad * 16 + lm) * 8];
      }
      #pragma unroll
      for (int mi = 0; mi < 4; mi++)
        #pragma unroll
        for (int ni = 0; ni < 4; ni++)
          acc[mi][ni] = __builtin_amdgcn_mfma_f32_16x16x32_f16(af[mi], bf[ni], acc[mi][ni], 0, 0, 0);
    }
  }
  #pragma unroll
  for (int mi = 0; mi < 4; mi++) {
    int gr0 = m0 + wm + mi * 16 + quad * 4;
    #pragma unroll
    for (int ni = 0; ni < 4; ni++) {
      int gc = n0 + wn + ni * 16 + lm;
      #pragma unroll
      for (int r = 0; r < 4; r++)
        atomicAdd(&Us[(size_t)(gr0 + r) * 256 + gc], acc[mi][ni][r] * (1.f / 4096.f));
    }
  }
}

// ---------------- Final: denorm + channel projection ----------------

__global__ __launch_bounds__(256) void final_k(const float* __restrict__ y0,
                                               const float* __restrict__ stats,
                                               const float* __restrict__ aw,
                                               const float* __restrict__ ab,
                                               const float* __restrict__ mlp_b,
                                               const float* __restrict__ pw,
                                               const float* __restrict__ pb,
                                               float* __restrict__ out) {
  int b = blockIdx.y;
  int p0 = blockIdx.x * 8;
  int tid = threadIdx.x;
  __shared__ float ys[32 * 8];
  __shared__ float pws[32 * 32];
  for (int t = tid; t < 1024; t += 256) pws[t] = pw[t];
  int c = tid >> 3, pl = tid & 7;
  int row = b * 32 + c;
  float mean = stats[row], sd = stats[512 + row];
  float raw = y0[(size_t)row * 512 + p0 + pl];
  float v = ((raw + mlp_b[0]) - ab[c]) / (aw[c] + 1e-10f) * sd + mean;
  ys[c * 8 + pl] = v;
  __syncthreads();
  int co = tid & 31; int pl2 = tid >> 5;
  float accv = pb[co];
  #pragma unroll
  for (int cc = 0; cc < 32; cc++) accv += ys[cc * 8 + pl2] * pws[cc * 32 + co];
  out[(size_t)b * 512 * 32 + (size_t)(p0 + pl2) * 32 + co] = accv;
}

// ---------------- launch ----------------

extern "C" void kernel_launch(void* const* d_in, const int* in_sizes, int n_in,
                              void* d_out, int out_size, void* d_ws, size_t ws_size,
                              hipStream_t stream) {
  const float* x_enc = (const float*)d_in[0];
  const float* aw = (const float*)d_in[4];
  const float* ab = (const float*)d_in[5];
  const float* wr[3] = {(const float*)d_in[6], (const float*)d_in[8], (const float*)d_in[10]};
  const float* wi[3] = {(const float*)d_in[7], (const float*)d_in[9], (const float*)d_in[11]};
  const float* mlp_w = (const float*)d_in[12];
  const float* mlp_b = (const float*)d_in[13];
  const float* proj_w = (const float*)d_in[14];
  const float* proj_b = (const float*)d_in[15];
  const float* Am[3]  = {(const float*)d_in[16], (const float*)d_in[19], (const float*)d_in[22]};
  const float* Bv[3]  = {(const float*)d_in[17], (const float*)d_in[20], (const float*)d_in[23]};
  const float* Em[3]  = {(const float*)d_in[18], (const float*)d_in[21], (const float*)d_in[24]};

  float* w = (float*)d_ws;
  float* F     = w; w += 512 * 512;
  float* stats = w; w += 1024;
  float* Kry   = w; w += 3 * 512 * 256;
  float* R     = w; w += 3 * 2 * 65536;
  float* U     = w; w += 3 * 512 * 256;   // U and Ttot contiguous (zeroed together)
  float* Ttot  = w; w += 512 * 512;
  float* Et    = w; w += 3 * 256 * 512;
  float* y0    = w; w += 512 * 512;
  float* Pp    = w; w += 3 * 65536 * 2;   // 3 slabs always (small)
  _Float16* Qf = (_Float16*)w;

  // f16 buffers: batched (3 slabs) if ws allows, else 1 shared slab per-scale loop
  size_t base_bytes = (size_t)((char*)Qf - (char*)d_ws);
  size_t slab_bytes = (size_t)(8388608 + 4194304) * 2;   // Qf + Wb per slab
  int nS = (ws_size >= base_bytes + 3 * slab_bytes) ? 3 : 1;
  _Float16* Wb = Qf + (size_t)nS * 8388608;

  revin_k<<<512, 256, 0, stream>>>(x_enc, aw, ab, F, stats);
  prep_k<<<4867, 256, 0, stream>>>(Am[0], Am[1], Am[2], Bv[0], Bv[1], Bv[2],
                                   Em[0], Em[1], Em[2], R, Kry, Et, U);

  // Krylov doubling: Kry rows [2^j .. 2^(j+1)) = Kry[0..2^j) @ R_j ; R_{j+1} = R_j @ R_j
  for (int j = 0; j < 9; j++) {
    GJobs P{};
    int M = 1 << j;
    int cur = j & 1;
    int nz = 0;
    for (int s = 0; s < 3; s++) {
      float* Ks = Kry + (size_t)s * 131072;
      float* Rj = R + (size_t)s * 131072 + (size_t)cur * 65536;
      float* Rn = R + (size_t)s * 131072 + (size_t)(1 - cur) * 65536;
      P.j[nz++] = {Ks, Rj, Ks + (size_t)M * 256, nullptr, M, 256, 256, 0, 256, 0};
      if (j < 8) P.j[nz++] = {Rj, Rj, Rn, nullptr, 256, 256, 256, 0, 256, 0};
    }
    gemm32_k<<<dim3(8, 8, nz), 256, 0, stream>>>(P);
  }

  // Q build (2-phase), WbT build, U = Q @ Wb via MFMA (split-K 16, atomics)
  if (nS == 3) {
    qbuildA_k<<<768, 256, 0, stream>>>(Kry, (float2*)Pp, 0);
    qbuildB_k<<<768, 256, 0, stream>>>(Kry, (const float2*)Pp, Qf, 0);
    wbigT_k<<<768, 256, 0, stream>>>(wr[0], wi[0], wr[1], wi[1], wr[2], wi[2], Wb, 0);
    umfma_k<<<dim3(4, 2, 48), 256, 0, stream>>>(Qf, Wb, U, 0);
  } else {
    for (int s = 0; s < 3; s++) {
      qbuildA_k<<<256, 256, 0, stream>>>(Kry, (float2*)Pp, s);
      qbuildB_k<<<256, 256, 0, stream>>>(Kry, (const float2*)Pp, Qf, s);
      wbigT_k<<<256, 256, 0, stream>>>(wr[0], wi[0], wr[1], wi[1], wr[2], wi[2], Wb, s);
      umfma_k<<<dim3(4, 2, 16), 256, 0, stream>>>(Qf, Wb, U, s);
    }
  }

  // Ttot += mlp_w[s] * U_s @ Et_s
  {
    GJobs P{};
    for (int s = 0; s < 3; s++)
      P.j[s] = {U + (size_t)s * 131072, Et + (size_t)s * 131072, Ttot,
                mlp_w + s, 512, 512, 256, 0, 256, 1};
    gemm32_k<<<dim3(16, 16, 3), 256, 0, stream>>>(P);
  }

  // y0 = F @ Ttot
  {
    GJobs P{};
    P.j[0] = {F, Ttot, y0, nullptr, 512, 512, 512, 0, 512, 0};
    gemm32_k<<<dim3(16, 16, 1), 256, 0, stream>>>(P);
  }

  final_k<<<dim3(64, 16), 256, 0, stream>>>(y0, stats, aw, ab, mlp_b, proj_w, proj_b,
                                            (float*)d_out);
}